// Round 9
// baseline (203.567 us; speedup 1.0000x reference)
//
#include <hip/hip_runtime.h>

// GraphSAGE 2-layer forward.
// Round 9: GEMM restructured for occupancy + decoupled A-path:
//   - A frags loaded global->register directly (row-major, 16B/lane), 2-deep
//     register prefetch, fully-unrolled K loop (static reg indexing).
//   - B-only LDS dbuf (16KB), BK=64 with 8-slot XOR swizzle (0-conflict,
//     round-4-proven; round-6's 4-slot variant measured 1.6M conflicts).
//   - wave tile 32x64 (acc 32 VGPR) -> ~120 VGPR, 4 blocks/CU (50% occ).
//   - counted vmcnt(6): next tile's 4 A-loads + 2 B-stages stay in flight.
// CSR bucket-sort build, fp8 y1 gather, casts unchanged from round 8.

#define N_NODES 50000
#define N_EDGES 800000
#define RNB 196
#define REPB 4096
#define BCAP 8192

typedef unsigned short ushort_t;
typedef __attribute__((ext_vector_type(8))) short short8v;   // 8 bf16
typedef __attribute__((ext_vector_type(4))) float f32x4;
typedef __attribute__((ext_vector_type(2))) float f32x2;

__device__ __forceinline__ float b2f(ushort_t u) {
    union { unsigned int i; float f; } v; v.i = (unsigned int)u << 16; return v.f;
}
__device__ __forceinline__ ushort_t f2b(float f) {
    union { float f; unsigned int i; } v; v.f = f;
    unsigned int r = 0x7fffu + ((v.i >> 16) & 1u);   // RNE
    return (ushort_t)((v.i + r) >> 16);
}

__device__ __forceinline__ void gload_lds16(const void* gsrc, void* ldsdst) {
    auto* l3 = reinterpret_cast<__attribute__((address_space(3))) unsigned int*>(
        reinterpret_cast<uintptr_t>(ldsdst));
    __builtin_amdgcn_global_load_lds(
        reinterpret_cast<const unsigned int*>(gsrc), l3, 16, 0, 0);
}

// ---------------- CSR build via MSD bucket sort ----------------
__global__ __launch_bounds__(256) void mhist(
    const int* __restrict__ ei, int* __restrict__ ghist, int E)
{
    __shared__ int h[256];
    int t = threadIdx.x;
    h[t] = 0;
    __syncthreads();
    int base = blockIdx.x * REPB;
    int lim  = min(base + REPB, E);
    for (int i = base + t; i < lim; i += 256)
        atomicAdd(&h[ei[E + i] >> 8], 1);
    __syncthreads();
    if (t < RNB) ghist[t * RNB + blockIdx.x] = h[t];   // digit-major
}

#define SCAN_B 256
__global__ __launch_bounds__(256) void scan1(
    const int* __restrict__ in, int* __restrict__ excl,
    int* __restrict__ bsum, int N)
{
    __shared__ int s[SCAN_B];
    int t = threadIdx.x;
    int i = blockIdx.x * SCAN_B + t;
    int v = (i < N) ? in[i] : 0;
    s[t] = v;
    __syncthreads();
    for (int off = 1; off < SCAN_B; off <<= 1) {
        int add = (t >= off) ? s[t - off] : 0;
        __syncthreads();
        s[t] += add;
        __syncthreads();
    }
    if (i < N) excl[i] = s[t] - v;
    if (t == SCAN_B - 1) bsum[blockIdx.x] = s[t];
}

__global__ __launch_bounds__(256) void scan2(int* __restrict__ bsum, int nb)
{
    __shared__ int s[SCAN_B];
    int t = threadIdx.x;
    int v = (t < nb) ? bsum[t] : 0;
    s[t] = v;
    __syncthreads();
    for (int off = 1; off < 256; off <<= 1) {
        int add = (t >= off) ? s[t - off] : 0;
        __syncthreads();
        s[t] += add;
        __syncthreads();
    }
    if (t < nb) bsum[t] = s[t] - v;
}

__global__ __launch_bounds__(256) void scan3g(
    int* __restrict__ excl, const int* __restrict__ bsum, int N)
{
    int i = blockIdx.x * SCAN_B + threadIdx.x;
    if (i < N) excl[i] += bsum[blockIdx.x];
}

__global__ __launch_bounds__(256) void mscatter(
    const int* __restrict__ ei, const int* __restrict__ gscan,
    unsigned* __restrict__ packed, int E)
{
    __shared__ int cur[256];
    int t = threadIdx.x;
    if (t < RNB) cur[t] = gscan[t * RNB + blockIdx.x];
    __syncthreads();
    int base = blockIdx.x * REPB;
    int lim  = min(base + REPB, E);
    for (int i = base + t; i < lim; i += 256) {
        int d = ei[E + i], s = ei[i];
        int pos = atomicAdd(&cur[d >> 8], 1);
        packed[pos] = ((unsigned)d << 16) | (unsigned)s;
    }
}

__global__ __launch_bounds__(256) void bucket_sort(
    const unsigned* __restrict__ packed, const int* __restrict__ gscan,
    int* __restrict__ col, int* __restrict__ rp, int E)
{
    __shared__ unsigned k1[BCAP];
    __shared__ unsigned k2[BCAP];
    __shared__ int h[256], ss[256], ex[256], cur[256];

    int b = blockIdx.x, t = threadIdx.x;
    int start = gscan[b * RNB];
    int end   = (b + 1 < RNB) ? gscan[(b + 1) * RNB] : E;
    int sz    = min(end - start, BCAP);

    for (int i = t; i < sz; i += 256) k1[i] = packed[start + i];
    h[t] = 0;
    __syncthreads();
    for (int i = t; i < sz; i += 256)
        atomicAdd(&h[(k1[i] >> 16) & 255], 1);
    __syncthreads();
    ss[t] = h[t];
    __syncthreads();
    for (int off = 1; off < 256; off <<= 1) {
        int add = (t >= off) ? ss[t - off] : 0;
        __syncthreads();
        ss[t] += add;
        __syncthreads();
    }
    ex[t] = ss[t] - h[t];
    cur[t] = ex[t];
    __syncthreads();
    for (int i = t; i < sz; i += 256) {
        unsigned key = k1[i];
        int pos = atomicAdd(&cur[(key >> 16) & 255], 1);
        k2[pos] = key;
    }
    __syncthreads();
    for (int i = t; i < sz; i += 256)
        col[start + i] = (int)(k2[i] & 0xFFFFu);
    int dst = (b << 8) + t;
    if (dst <= N_NODES) rp[dst] = start + ex[t];
}

// ---------------- casts ----------------
__global__ __launch_bounds__(256) void cast_f32_bf16(
    const float* __restrict__ in, ushort_t* __restrict__ out, int n4)
{
    int i = blockIdx.x * blockDim.x + threadIdx.x;
    int stride = gridDim.x * blockDim.x;
    for (; i < n4; i += stride) {
        float4 v = ((const float4*)in)[i];
        ushort4 o;
        o.x = f2b(v.x); o.y = f2b(v.y); o.z = f2b(v.z); o.w = f2b(v.w);
        ((ushort4*)out)[i] = o;
    }
}

// Bt1[512][256] = [W1l|W1r]^T ; Bt2[256][256] = [W2l|W2r]^T  (bf16, [n][k])
__global__ __launch_bounds__(256) void build_bt(
    const float* __restrict__ W1l, const float* __restrict__ W1r,
    const float* __restrict__ W2l, const float* __restrict__ W2r,
    ushort_t* __restrict__ Bt1, ushort_t* __restrict__ Bt2)
{
    int i = blockIdx.x * 256 + threadIdx.x;
    if (i < 512 * 256) {
        int n = i >> 8, k = i & 255;
        float v = (n < 256) ? W1l[k * 256 + n] : W1r[k * 256 + (n - 256)];
        Bt1[i] = f2b(v);
    }
    int j = i - 512 * 256;
    if (j >= 0 && j < 256 * 256) {
        int n = j >> 8, k = j & 255;
        float v = (n < 128) ? W2l[k * 128 + n] : W2r[k * 128 + (n - 128)];
        Bt2[j] = f2b(v);
    }
}

// ---------------- bf16 MFMA GEMM, A-in-register ----------------
// C[M, Ncols] = A[M,256] @ Bt^T (Bt [n][256] bf16).  Block: 256 thr = 4
// waves stacked vertically; block tile 128 rows x 64 cols; wave 32x64
// (mi 2 x nj 4).  BK=64 -> 4 kt.  B via LDS dbuf 16KB, 8-slot swizzle.
// A frags global->reg, 2-deep prefetch.  MODE 0: col0<256 -> y8 fp8 (ld
// 256), else y2b bf16 (ld 256, +bias).  MODE 1: col0<128 -> zb bf16 (ld
// 128), else outf f32 (ld 128, +bias).
template<int MODE>
__global__ __launch_bounds__(256, 4) void gemm_areg(
    const ushort_t* __restrict__ A, const ushort_t* __restrict__ Bt,
    const float* __restrict__ bias, unsigned char* __restrict__ out8,
    ushort_t* __restrict__ outb, float* __restrict__ outf, int M)
{
    __shared__ ushort_t Bs[2][64][64];   // 2 x 8 KB, row = 128 B

    const int t    = threadIdx.x;
    const int lane = t & 63;
    const int wv   = t >> 6;              // wave 0..3, 32 rows each
    const int col0 = blockIdx.x * 64;     // col fastest -> A slab L2 reuse
    const int row0 = blockIdx.y * 128;

    // per-lane A row/col bases
    const int arow[2] = {
        min(row0 + wv * 32 + 0  + (lane & 15), M - 1),
        min(row0 + wv * 32 + 16 + (lane & 15), M - 1) };
    const int kq = (lane >> 4) << 3;      // 8-elem k sub-slot

    auto stageB = [&](int kt, int buf) {
        #pragma unroll
        for (int i = 0; i < 2; ++i) {
            int o   = (i * 256 + t) * 16;                 // linear dest byte
            int row = o >> 7;                              // B col index
            int kb  = (o & 127) ^ ((row & 7) << 4);        // inv-swizzled src
            gload_lds16(Bt + (size_t)(col0 + row) * 256 + kt * 64 + (kb >> 1),
                        (char*)&Bs[buf][0][0] + i * 4096 + wv * 1024);
        }
    };

    short8v af[2][2][2];   // [buf][mi][ks]
    f32x4 acc[2][4] = {};

    // prologue: A(0) + B(0)
    #pragma unroll
    for (int mi = 0; mi < 2; ++mi)
        #pragma unroll
        for (int ks = 0; ks < 2; ++ks)
            af[0][mi][ks] = *(const short8v*)(A + (size_t)arow[mi] * 256
                                              + ks * 32 + kq);
    stageB(0, 0);

    #pragma unroll
    for (int kt = 0; kt < 4; ++kt) {
        const int buf = kt & 1;
        if (kt < 3) {
            #pragma unroll
            for (int mi = 0; mi < 2; ++mi)
                #pragma unroll
                for (int ks = 0; ks < 2; ++ks)
                    af[buf ^ 1][mi][ks] =
                        *(const short8v*)(A + (size_t)arow[mi] * 256
                                          + (kt + 1) * 64 + ks * 32 + kq);
            stageB(kt + 1, buf ^ 1);
            __builtin_amdgcn_sched_barrier(0);
            asm volatile("s_waitcnt vmcnt(6)");    // A(kt)+B(kt) landed
            __builtin_amdgcn_sched_barrier(0);
        } else {
            __builtin_amdgcn_sched_barrier(0);
            asm volatile("s_waitcnt vmcnt(0)");
            __builtin_amdgcn_sched_barrier(0);
        }
        __builtin_amdgcn_s_barrier();
        __builtin_amdgcn_sched_barrier(0);

        short8v bg[4][2];
        #pragma unroll
        for (int nj = 0; nj < 4; ++nj) {
            #pragma unroll
            for (int ks = 0; ks < 2; ++ks) {
                int row = (nj << 4) + (lane & 15);
                int b   = ((ks << 6) + ((lane >> 4) << 4)) ^ ((row & 7) << 4);
                bg[nj][ks] = *(const short8v*)((const char*)&Bs[buf][0][0]
                                               + row * 128 + b);
            }
        }

        __builtin_amdgcn_s_setprio(1);
        #pragma unroll
        for (int ks = 0; ks < 2; ++ks)
            #pragma unroll
            for (int mi = 0; mi < 2; ++mi)
                #pragma unroll
                for (int nj = 0; nj < 4; ++nj)
                    acc[mi][nj] = __builtin_amdgcn_mfma_f32_16x16x32_bf16(
                        af[buf][mi][ks], bg[nj][ks], acc[mi][nj], 0, 0, 0);
        __builtin_amdgcn_s_setprio(0);

        __builtin_amdgcn_sched_barrier(0);
        __builtin_amdgcn_s_barrier();          // release buf for kt+2 staging
        __builtin_amdgcn_sched_barrier(0);
    }

    // epilogue: C/D layout col=lane&15, row=(lane>>4)*4+r ; branch is
    // block-uniform (64 | 256 and 64 | 128).
    #pragma unroll
    for (int mi = 0; mi < 2; ++mi) {
        #pragma unroll
        for (int nj = 0; nj < 4; ++nj) {
            int c = col0 + (nj << 4) + (lane & 15);
            #pragma unroll
            for (int r = 0; r < 4; ++r) {
                int row = row0 + wv * 32 + (mi << 4) + ((lane >> 4) << 2) + r;
                if (row >= M) continue;
                float v = acc[mi][nj][r];
                if (MODE == 0) {
                    if (col0 < 256) {
                        unsigned p = __builtin_amdgcn_cvt_pk_fp8_f32(v, v, 0, false);
                        out8[(size_t)row * 256 + c] = (unsigned char)(p & 0xFFu);
                    } else {
                        outb[(size_t)row * 256 + (c - 256)] = f2b(v + bias[c - 256]);
                    }
                } else {
                    if (col0 < 128) {
                        outb[(size_t)row * 128 + c] = f2b(v);
                    } else {
                        outf[(size_t)row * 128 + (c - 128)] = v + bias[c - 128];
                    }
                }
            }
        }
    }
}

// ---------------- fused gather 1: h = relu(mean_fp8(y1[nbr]) + y2) --------
__global__ __launch_bounds__(256) void fused_gather1(
    const unsigned char* __restrict__ y8, const ushort_t* __restrict__ y2b,
    const int* __restrict__ rp, const int* __restrict__ col,
    ushort_t* __restrict__ h, int N)
{
    int gid  = blockIdx.x * blockDim.x + threadIdx.x;
    int node = gid >> 6;
    int lane = gid & 63;
    if (node >= N) return;
    int rs = rp[node], re = rp[node + 1];

    float acc[4] = {0.f, 0.f, 0.f, 0.f};
    for (int base = rs; base < re; base += 64) {
        int m = re - base; if (m > 64) m = 64;
        int c = (lane < m) ? col[base + lane] : 0;
        int j = 0;
        for (; j + 8 <= m; j += 8) {
            unsigned tv[8];
            #pragma unroll
            for (int q = 0; q < 8; ++q) {
                int sq = __shfl(c, j + q);
                tv[q] = *(const unsigned*)(y8 + (size_t)sq * 256 + lane * 4);
            }
            #pragma unroll
            for (int q = 0; q < 8; ++q) {
                f32x2 lo = __builtin_amdgcn_cvt_pk_f32_fp8(tv[q], false);
                f32x2 hi = __builtin_amdgcn_cvt_pk_f32_fp8(tv[q], true);
                acc[0] += lo[0]; acc[1] += lo[1];
                acc[2] += hi[0]; acc[3] += hi[1];
            }
        }
        for (; j < m; ++j) {
            int sq = __shfl(c, j);
            unsigned tq = *(const unsigned*)(y8 + (size_t)sq * 256 + lane * 4);
            f32x2 lo = __builtin_amdgcn_cvt_pk_f32_fp8(tq, false);
            f32x2 hi = __builtin_amdgcn_cvt_pk_f32_fp8(tq, true);
            acc[0] += lo[0]; acc[1] += lo[1];
            acc[2] += hi[0]; acc[3] += hi[1];
        }
    }

    float s = 1.0f / (float)max(re - rs, 1);
    ushort4 t2 = *(const ushort4*)(y2b + (size_t)node * 256 + lane * 4);
    ushort4 o;
    o.x = f2b(fmaxf(acc[0] * s + b2f(t2.x), 0.f));
    o.y = f2b(fmaxf(acc[1] * s + b2f(t2.y), 0.f));
    o.z = f2b(fmaxf(acc[2] * s + b2f(t2.z), 0.f));
    o.w = f2b(fmaxf(acc[3] * s + b2f(t2.w), 0.f));
    *(ushort4*)(h + (size_t)node * 256 + lane * 4) = o;
}

// ---------------- fused gather 2: out += mean(zb[nbr]) --------------------
__global__ __launch_bounds__(256) void fused_gather2(
    const ushort_t* __restrict__ zb, const int* __restrict__ rp,
    const int* __restrict__ col, float* __restrict__ out, int N)
{
    int gid  = blockIdx.x * blockDim.x + threadIdx.x;
    int node = gid >> 6;
    int lane = gid & 63;
    if (node >= N) return;
    int rs = rp[node], re = rp[node + 1];

    float acc[2] = {0.f, 0.f};
    for (int base = rs; base < re; base += 64) {
        int m = re - base; if (m > 64) m = 64;
        int c = (lane < m) ? col[base + lane] : 0;
        int j = 0;
        for (; j + 8 <= m; j += 8) {
            ushort2 tv[8];
            #pragma unroll
            for (int q = 0; q < 8; ++q) {
                int sq = __shfl(c, j + q);
                tv[q] = *(const ushort2*)(zb + (size_t)sq * 128 + lane * 2);
            }
            #pragma unroll
            for (int q = 0; q < 8; ++q) {
                acc[0] += b2f(tv[q].x); acc[1] += b2f(tv[q].y);
            }
        }
        for (; j < m; ++j) {
            int src = __shfl(c, j);
            ushort2 tq = *(const ushort2*)(zb + (size_t)src * 128 + lane * 2);
            acc[0] += b2f(tq.x); acc[1] += b2f(tq.y);
        }
    }

    float s = 1.0f / (float)max(re - rs, 1);
    float2 p = *(float2*)(out + (size_t)node * 128 + lane * 2);
    p.x += acc[0] * s; p.y += acc[1] * s;
    *(float2*)(out + (size_t)node * 128 + lane * 2) = p;
}

extern "C" void kernel_launch(void* const* d_in, const int* in_sizes, int n_in,
                              void* d_out, int out_size, void* d_ws, size_t ws_size,
                              hipStream_t stream)
{
    const float* x   = (const float*)d_in[0];
    const int*   ei  = (const int*)d_in[1];
    const float* W1l = (const float*)d_in[2];
    const float* b1  = (const float*)d_in[3];
    const float* W1r = (const float*)d_in[4];
    const float* W2l = (const float*)d_in[5];
    const float* b2  = (const float*)d_in[6];
    const float* W2r = (const float*)d_in[7];
    float* out = (float*)d_out;

    const int N = N_NODES, E = N_EDGES;
    const int HTOT = RNB * RNB;

    // workspace layout (256 B aligned)
    const size_t off_rp     = 0;
    const size_t off_col    = 204800;
    const size_t off_packed = off_col + 3200000;
    const size_t off_ghist  = off_packed + 3200000;
    const size_t off_gscan  = off_ghist + 160000;
    const size_t off_bsumR  = off_gscan + 160000;
    const size_t off_xb     = off_bsumR + 2048;                // bf16 [N][256]; h overlays
    const size_t off_y8     = off_xb  + (size_t)N * 256 * 2;   // fp8  [N][256]; zb overlays
    const size_t off_y2b    = off_y8  + (size_t)N * 256;       // bf16 [N][256]
    const size_t off_bt1    = off_y2b + (size_t)N * 256 * 2;
    const size_t off_bt2    = off_bt1 + 512 * 256 * 2;
    const size_t required   = off_bt2 + 256 * 256 * 2;         // ~71.3 MB
    if (ws_size < required) return;

    char* ws = (char*)d_ws;
    int*           rp     = (int*)(ws + off_rp);
    int*           col    = (int*)(ws + off_col);
    unsigned*      packed = (unsigned*)(ws + off_packed);
    int*           ghist  = (int*)(ws + off_ghist);
    int*           gscan  = (int*)(ws + off_gscan);
    int*           bsumR  = (int*)(ws + off_bsumR);
    ushort_t*      xb     = (ushort_t*)(ws + off_xb);
    ushort_t*      h      = (ushort_t*)(ws + off_xb);  // overlays xb (dead after GEMM1)
    unsigned char* y8     = (unsigned char*)(ws + off_y8);
    ushort_t*      zb     = (ushort_t*)(ws + off_y8);  // overlays y8 (dead after gather1)
    ushort_t*      y2b    = (ushort_t*)(ws + off_y2b);
    ushort_t*      Bt1    = (ushort_t*)(ws + off_bt1);
    ushort_t*      Bt2    = (ushort_t*)(ws + off_bt2);

    const int snb = (HTOT + SCAN_B - 1) / SCAN_B;   // 151
    const int mt  = (N + 127) / 128;                // 391 row tiles

    // ---- CSR build: MSD bucket sort ----
    hipLaunchKernelGGL(mhist, dim3(RNB), dim3(256), 0, stream, ei, ghist, E);
    hipLaunchKernelGGL(scan1, dim3(snb), dim3(SCAN_B), 0, stream, ghist, gscan, bsumR, HTOT);
    hipLaunchKernelGGL(scan2, dim3(1), dim3(SCAN_B), 0, stream, bsumR, snb);
    hipLaunchKernelGGL(scan3g, dim3(snb), dim3(SCAN_B), 0, stream, gscan, bsumR, HTOT);
    hipLaunchKernelGGL(mscatter, dim3(RNB), dim3(256), 0, stream, ei, gscan, packed, E);
    hipLaunchKernelGGL(bucket_sort, dim3(RNB), dim3(256), 0, stream, packed, gscan, col, rp, E);

    // ---- casts ----
    hipLaunchKernelGGL(cast_f32_bf16, dim3(2048), dim3(256), 0, stream,
                       x, xb, N * 256 / 4);
    hipLaunchKernelGGL(build_bt, dim3(768), dim3(256), 0, stream,
                       W1l, W1r, W2l, W2r, Bt1, Bt2);

    // ---- layer 1: [y8|y2b] = xb@[W1l|W1r] (+b1); h = relu(mean(y8)+y2b) --
    hipLaunchKernelGGL((gemm_areg<0>), dim3(8, mt), dim3(256), 0, stream,
                       xb, Bt1, b1, y8, y2b, (float*)nullptr, N);
    hipLaunchKernelGGL(fused_gather1, dim3((N + 3) / 4), dim3(256), 0, stream,
                       y8, y2b, rp, col, h, N);

    // ---- layer 2: [zb|out] = h@[W2l|W2r] (+b2 on out); out += mean(zb) ----
    hipLaunchKernelGGL((gemm_areg<1>), dim3(4, mt), dim3(256), 0, stream,
                       h, Bt2, b2, (unsigned char*)nullptr, zb, out, N);
    hipLaunchKernelGGL(fused_gather2, dim3((N + 3) / 4), dim3(256), 0, stream,
                       zb, rp, col, out, N);
}

// Round 10
// 184.546 us; speedup vs baseline: 1.1031x; 1.1031x over previous
//
#include <hip/hip_runtime.h>

// GraphSAGE 2-layer forward.
// Round 10: A-stationary GEMM -- wave holds its 16-row A-slice (full K=256,
// 32 VGPR) loaded ONCE; B (L2-resident, 256-512KB) cycles through a single
// 32KB LDS buffer per 64-col tile. Per-tile drain waits on L2 (~250cy), not
// HBM; stage issued before stores + in-order vmcnt(16) avoids store-ack
// drain. Grid (2 col-groups, 782 row-slabs): A fetched exactly 2x, 6
// blocks/CU for balance, ~50% occupancy target.
// CSR bucket sort, fp8 y1 gather, casts unchanged from round 8.

#define N_NODES 50000
#define N_EDGES 800000
#define RNB 196
#define REPB 4096
#define BCAP 8192

typedef unsigned short ushort_t;
typedef __attribute__((ext_vector_type(8))) short short8v;   // 8 bf16
typedef __attribute__((ext_vector_type(4))) float f32x4;
typedef __attribute__((ext_vector_type(2))) float f32x2;

__device__ __forceinline__ float b2f(ushort_t u) {
    union { unsigned int i; float f; } v; v.i = (unsigned int)u << 16; return v.f;
}
__device__ __forceinline__ ushort_t f2b(float f) {
    union { float f; unsigned int i; } v; v.f = f;
    unsigned int r = 0x7fffu + ((v.i >> 16) & 1u);   // RNE
    return (ushort_t)((v.i + r) >> 16);
}

__device__ __forceinline__ void gload_lds16(const void* gsrc, void* ldsdst) {
    auto* l3 = reinterpret_cast<__attribute__((address_space(3))) unsigned int*>(
        reinterpret_cast<uintptr_t>(ldsdst));
    __builtin_amdgcn_global_load_lds(
        reinterpret_cast<const unsigned int*>(gsrc), l3, 16, 0, 0);
}

// ---------------- CSR build via MSD bucket sort ----------------
__global__ __launch_bounds__(256) void mhist(
    const int* __restrict__ ei, int* __restrict__ ghist, int E)
{
    __shared__ int h[256];
    int t = threadIdx.x;
    h[t] = 0;
    __syncthreads();
    int base = blockIdx.x * REPB;
    int lim  = min(base + REPB, E);
    for (int i = base + t; i < lim; i += 256)
        atomicAdd(&h[ei[E + i] >> 8], 1);
    __syncthreads();
    if (t < RNB) ghist[t * RNB + blockIdx.x] = h[t];   // digit-major
}

#define SCAN_B 256
__global__ __launch_bounds__(256) void scan1(
    const int* __restrict__ in, int* __restrict__ excl,
    int* __restrict__ bsum, int N)
{
    __shared__ int s[SCAN_B];
    int t = threadIdx.x;
    int i = blockIdx.x * SCAN_B + t;
    int v = (i < N) ? in[i] : 0;
    s[t] = v;
    __syncthreads();
    for (int off = 1; off < SCAN_B; off <<= 1) {
        int add = (t >= off) ? s[t - off] : 0;
        __syncthreads();
        s[t] += add;
        __syncthreads();
    }
    if (i < N) excl[i] = s[t] - v;
    if (t == SCAN_B - 1) bsum[blockIdx.x] = s[t];
}

__global__ __launch_bounds__(256) void scan2(int* __restrict__ bsum, int nb)
{
    __shared__ int s[SCAN_B];
    int t = threadIdx.x;
    int v = (t < nb) ? bsum[t] : 0;
    s[t] = v;
    __syncthreads();
    for (int off = 1; off < 256; off <<= 1) {
        int add = (t >= off) ? s[t - off] : 0;
        __syncthreads();
        s[t] += add;
        __syncthreads();
    }
    if (t < nb) bsum[t] = s[t] - v;
}

__global__ __launch_bounds__(256) void scan3g(
    int* __restrict__ excl, const int* __restrict__ bsum, int N)
{
    int i = blockIdx.x * SCAN_B + threadIdx.x;
    if (i < N) excl[i] += bsum[blockIdx.x];
}

__global__ __launch_bounds__(256) void mscatter(
    const int* __restrict__ ei, const int* __restrict__ gscan,
    unsigned* __restrict__ packed, int E)
{
    __shared__ int cur[256];
    int t = threadIdx.x;
    if (t < RNB) cur[t] = gscan[t * RNB + blockIdx.x];
    __syncthreads();
    int base = blockIdx.x * REPB;
    int lim  = min(base + REPB, E);
    for (int i = base + t; i < lim; i += 256) {
        int d = ei[E + i], s = ei[i];
        int pos = atomicAdd(&cur[d >> 8], 1);
        packed[pos] = ((unsigned)d << 16) | (unsigned)s;
    }
}

__global__ __launch_bounds__(256) void bucket_sort(
    const unsigned* __restrict__ packed, const int* __restrict__ gscan,
    int* __restrict__ col, int* __restrict__ rp, int E)
{
    __shared__ unsigned k1[BCAP];
    __shared__ unsigned k2[BCAP];
    __shared__ int h[256], ss[256], ex[256], cur[256];

    int b = blockIdx.x, t = threadIdx.x;
    int start = gscan[b * RNB];
    int end   = (b + 1 < RNB) ? gscan[(b + 1) * RNB] : E;
    int sz    = min(end - start, BCAP);

    for (int i = t; i < sz; i += 256) k1[i] = packed[start + i];
    h[t] = 0;
    __syncthreads();
    for (int i = t; i < sz; i += 256)
        atomicAdd(&h[(k1[i] >> 16) & 255], 1);
    __syncthreads();
    ss[t] = h[t];
    __syncthreads();
    for (int off = 1; off < 256; off <<= 1) {
        int add = (t >= off) ? ss[t - off] : 0;
        __syncthreads();
        ss[t] += add;
        __syncthreads();
    }
    ex[t] = ss[t] - h[t];
    cur[t] = ex[t];
    __syncthreads();
    for (int i = t; i < sz; i += 256) {
        unsigned key = k1[i];
        int pos = atomicAdd(&cur[(key >> 16) & 255], 1);
        k2[pos] = key;
    }
    __syncthreads();
    for (int i = t; i < sz; i += 256)
        col[start + i] = (int)(k2[i] & 0xFFFFu);
    int dst = (b << 8) + t;
    if (dst <= N_NODES) rp[dst] = start + ex[t];
}

// ---------------- casts ----------------
__global__ __launch_bounds__(256) void cast_f32_bf16(
    const float* __restrict__ in, ushort_t* __restrict__ out, int n4)
{
    int i = blockIdx.x * blockDim.x + threadIdx.x;
    int stride = gridDim.x * blockDim.x;
    for (; i < n4; i += stride) {
        float4 v = ((const float4*)in)[i];
        ushort4 o;
        o.x = f2b(v.x); o.y = f2b(v.y); o.z = f2b(v.z); o.w = f2b(v.w);
        ((ushort4*)out)[i] = o;
    }
}

// Bt1[512][256] = [W1l|W1r]^T ; Bt2[256][256] = [W2l|W2r]^T  (bf16, [n][k])
__global__ __launch_bounds__(256) void build_bt(
    const float* __restrict__ W1l, const float* __restrict__ W1r,
    const float* __restrict__ W2l, const float* __restrict__ W2r,
    ushort_t* __restrict__ Bt1, ushort_t* __restrict__ Bt2)
{
    int i = blockIdx.x * 256 + threadIdx.x;
    if (i < 512 * 256) {
        int n = i >> 8, k = i & 255;
        float v = (n < 256) ? W1l[k * 256 + n] : W1r[k * 256 + (n - 256)];
        Bt1[i] = f2b(v);
    }
    int j = i - 512 * 256;
    if (j >= 0 && j < 256 * 256) {
        int n = j >> 8, k = j & 255;
        float v = (n < 128) ? W2l[k * 128 + n] : W2r[k * 128 + (n - 128)];
        Bt2[j] = f2b(v);
    }
}

// ---------------- A-stationary bf16 MFMA GEMM ----------------
// C[M, 2*NT*64] = A[M,256] @ Bt^T, Bt [n][256] bf16.
// Block: 256 thr = 4 waves x 16 rows = 64 rows. blockIdx.x = col group g
// (NT 64-col tiles each), blockIdx.y = row slab (782).
// A-slice (16 rows x 256 k) resident in 8 short8v per lane, loaded once.
// B tile [64 cols][256 k] = 32 KB single LDS buffer, 8-slot XOR swizzle
// within each 512B col-row; staged via gload_lds (linear dest, inv-swz src).
// MODE 0 (N=512): g0 -> y8 fp8 (ld 256); g1 -> y2b bf16 + bias (ld 256).
// MODE 1 (N=256): g0 -> zb bf16 (ld 128); g1 -> outf f32 + bias (ld 128).
template<int NT, int MODE>
__global__ __launch_bounds__(256, 4) void gemm_astat(
    const ushort_t* __restrict__ A, const ushort_t* __restrict__ Bt,
    const float* __restrict__ bias, unsigned char* __restrict__ out8,
    ushort_t* __restrict__ outb, float* __restrict__ outf, int M)
{
    __shared__ ushort_t Bs[64][256];   // 32 KB, col-major rows of 512 B

    const int t    = threadIdx.x;
    const int lane = t & 63;
    const int wv   = t >> 6;
    const int g    = blockIdx.x;               // col group (uniform branch)
    const int row0 = blockIdx.y * 64 + wv * 16;
    const int cbase = g * NT * 64;             // first col of this group
    const int arow = min(row0 + (lane & 15), M - 1);
    const int kq   = (lane >> 4) << 3;         // k sub-slot (8 elems)

    // stage one 64-col B tile: linear LDS dest, inverse-swizzled source
    auto stage = [&](int ct) {
        #pragma unroll
        for (int i = 0; i < 8; ++i) {
            int o    = (i * 256 + t) * 16;     // dest byte 0..32767
            int colI = o >> 9;                 // B col within tile
            int inner = o & 511;
            int srcb = inner ^ ((colI & 7) << 4);
            gload_lds16(Bt + (size_t)(cbase + ct * 64 + colI) * 256 + (srcb >> 1),
                        (char*)&Bs[0][0] + i * 4096 + wv * 1024);
        }
    };

    // A-slice resident: 8 x short8v = 32 VGPR (full K)
    short8v af[8];
    #pragma unroll
    for (int ks = 0; ks < 8; ++ks)
        af[ks] = *(const short8v*)(A + (size_t)arow * 256 + ks * 32 + kq);

    stage(0);
    __builtin_amdgcn_sched_barrier(0);
    asm volatile("s_waitcnt vmcnt(0)");        // A + B(0) landed
    __builtin_amdgcn_sched_barrier(0);
    __builtin_amdgcn_s_barrier();
    __builtin_amdgcn_sched_barrier(0);

    #pragma unroll
    for (int ct = 0; ct < NT; ++ct) {
        f32x4 acc[4] = {};
        __builtin_amdgcn_s_setprio(1);
        #pragma unroll
        for (int ks = 0; ks < 8; ++ks) {
            short8v bg[4];
            #pragma unroll
            for (int nj = 0; nj < 4; ++nj) {
                int colI = (nj << 4) + (lane & 15);
                int b = ((ks << 6) + ((lane >> 4) << 4)) ^ ((colI & 7) << 4);
                bg[nj] = *(const short8v*)((const char*)&Bs[0][0]
                                           + colI * 512 + b);
            }
            #pragma unroll
            for (int nj = 0; nj < 4; ++nj)
                acc[nj] = __builtin_amdgcn_mfma_f32_16x16x32_bf16(
                    af[ks], bg[nj], acc[nj], 0, 0, 0);
        }
        __builtin_amdgcn_s_setprio(0);

        if (ct + 1 < NT) {
            __builtin_amdgcn_sched_barrier(0);
            __builtin_amdgcn_s_barrier();      // all waves done reading Bs
            __builtin_amdgcn_sched_barrier(0);
            stage(ct + 1);                     // 8 loads issued FIRST
            __builtin_amdgcn_sched_barrier(0);
        }

        // stores issued AFTER stage; vmcnt retires in order
        #pragma unroll
        for (int nj = 0; nj < 4; ++nj) {
            #pragma unroll
            for (int r = 0; r < 4; ++r) {
                int row = row0 + ((lane >> 4) << 2) + r;
                if (row >= M) continue;
                int local = ct * 64 + (nj << 4) + (lane & 15);
                float v = acc[nj][r];
                if (MODE == 0) {
                    if (g == 0) {
                        unsigned p = __builtin_amdgcn_cvt_pk_fp8_f32(v, v, 0, false);
                        out8[(size_t)row * 256 + local] = (unsigned char)(p & 0xFFu);
                    } else {
                        outb[(size_t)row * 256 + local] = f2b(v + bias[local]);
                    }
                } else {
                    if (g == 0) {
                        outb[(size_t)row * 128 + local] = f2b(v);
                    } else {
                        outf[(size_t)row * 128 + local] = v + bias[local];
                    }
                }
            }
        }

        if (ct + 1 < NT) {
            __builtin_amdgcn_sched_barrier(0);
            asm volatile("s_waitcnt vmcnt(16)");   // 8 stage loads retired
            __builtin_amdgcn_sched_barrier(0);
            __builtin_amdgcn_s_barrier();          // Bs(ct+1) valid for all
            __builtin_amdgcn_sched_barrier(0);
        }
    }
}

// ---------------- fused gather 1: h = relu(mean_fp8(y1[nbr]) + y2) --------
__global__ __launch_bounds__(256) void fused_gather1(
    const unsigned char* __restrict__ y8, const ushort_t* __restrict__ y2b,
    const int* __restrict__ rp, const int* __restrict__ col,
    ushort_t* __restrict__ h, int N)
{
    int gid  = blockIdx.x * blockDim.x + threadIdx.x;
    int node = gid >> 6;
    int lane = gid & 63;
    if (node >= N) return;
    int rs = rp[node], re = rp[node + 1];

    float acc[4] = {0.f, 0.f, 0.f, 0.f};
    for (int base = rs; base < re; base += 64) {
        int m = re - base; if (m > 64) m = 64;
        int c = (lane < m) ? col[base + lane] : 0;
        int j = 0;
        for (; j + 8 <= m; j += 8) {
            unsigned tv[8];
            #pragma unroll
            for (int q = 0; q < 8; ++q) {
                int sq = __shfl(c, j + q);
                tv[q] = *(const unsigned*)(y8 + (size_t)sq * 256 + lane * 4);
            }
            #pragma unroll
            for (int q = 0; q < 8; ++q) {
                f32x2 lo = __builtin_amdgcn_cvt_pk_f32_fp8(tv[q], false);
                f32x2 hi = __builtin_amdgcn_cvt_pk_f32_fp8(tv[q], true);
                acc[0] += lo[0]; acc[1] += lo[1];
                acc[2] += hi[0]; acc[3] += hi[1];
            }
        }
        for (; j < m; ++j) {
            int sq = __shfl(c, j);
            unsigned tq = *(const unsigned*)(y8 + (size_t)sq * 256 + lane * 4);
            f32x2 lo = __builtin_amdgcn_cvt_pk_f32_fp8(tq, false);
            f32x2 hi = __builtin_amdgcn_cvt_pk_f32_fp8(tq, true);
            acc[0] += lo[0]; acc[1] += lo[1];
            acc[2] += hi[0]; acc[3] += hi[1];
        }
    }

    float s = 1.0f / (float)max(re - rs, 1);
    ushort4 t2 = *(const ushort4*)(y2b + (size_t)node * 256 + lane * 4);
    ushort4 o;
    o.x = f2b(fmaxf(acc[0] * s + b2f(t2.x), 0.f));
    o.y = f2b(fmaxf(acc[1] * s + b2f(t2.y), 0.f));
    o.z = f2b(fmaxf(acc[2] * s + b2f(t2.z), 0.f));
    o.w = f2b(fmaxf(acc[3] * s + b2f(t2.w), 0.f));
    *(ushort4*)(h + (size_t)node * 256 + lane * 4) = o;
}

// ---------------- fused gather 2: out += mean(zb[nbr]) --------------------
__global__ __launch_bounds__(256) void fused_gather2(
    const ushort_t* __restrict__ zb, const int* __restrict__ rp,
    const int* __restrict__ col, float* __restrict__ out, int N)
{
    int gid  = blockIdx.x * blockDim.x + threadIdx.x;
    int node = gid >> 6;
    int lane = gid & 63;
    if (node >= N) return;
    int rs = rp[node], re = rp[node + 1];

    float acc[2] = {0.f, 0.f};
    for (int base = rs; base < re; base += 64) {
        int m = re - base; if (m > 64) m = 64;
        int c = (lane < m) ? col[base + lane] : 0;
        int j = 0;
        for (; j + 8 <= m; j += 8) {
            ushort2 tv[8];
            #pragma unroll
            for (int q = 0; q < 8; ++q) {
                int sq = __shfl(c, j + q);
                tv[q] = *(const ushort2*)(zb + (size_t)sq * 128 + lane * 2);
            }
            #pragma unroll
            for (int q = 0; q < 8; ++q) {
                acc[0] += b2f(tv[q].x); acc[1] += b2f(tv[q].y);
            }
        }
        for (; j < m; ++j) {
            int src = __shfl(c, j);
            ushort2 tq = *(const ushort2*)(zb + (size_t)src * 128 + lane * 2);
            acc[0] += b2f(tq.x); acc[1] += b2f(tq.y);
        }
    }

    float s = 1.0f / (float)max(re - rs, 1);
    float2 p = *(float2*)(out + (size_t)node * 128 + lane * 2);
    p.x += acc[0] * s; p.y += acc[1] * s;
    *(float2*)(out + (size_t)node * 128 + lane * 2) = p;
}

extern "C" void kernel_launch(void* const* d_in, const int* in_sizes, int n_in,
                              void* d_out, int out_size, void* d_ws, size_t ws_size,
                              hipStream_t stream)
{
    const float* x   = (const float*)d_in[0];
    const int*   ei  = (const int*)d_in[1];
    const float* W1l = (const float*)d_in[2];
    const float* b1  = (const float*)d_in[3];
    const float* W1r = (const float*)d_in[4];
    const float* W2l = (const float*)d_in[5];
    const float* b2  = (const float*)d_in[6];
    const float* W2r = (const float*)d_in[7];
    float* out = (float*)d_out;

    const int N = N_NODES, E = N_EDGES;
    const int HTOT = RNB * RNB;

    // workspace layout (256 B aligned)
    const size_t off_rp     = 0;
    const size_t off_col    = 204800;
    const size_t off_packed = off_col + 3200000;
    const size_t off_ghist  = off_packed + 3200000;
    const size_t off_gscan  = off_ghist + 160000;
    const size_t off_bsumR  = off_gscan + 160000;
    const size_t off_xb     = off_bsumR + 2048;                // bf16 [N][256]; h overlays
    const size_t off_y8     = off_xb  + (size_t)N * 256 * 2;   // fp8  [N][256]; zb overlays
    const size_t off_y2b    = off_y8  + (size_t)N * 256;       // bf16 [N][256]
    const size_t off_bt1    = off_y2b + (size_t)N * 256 * 2;
    const size_t off_bt2    = off_bt1 + 512 * 256 * 2;
    const size_t required   = off_bt2 + 256 * 256 * 2;         // ~71.3 MB
    if (ws_size < required) return;

    char* ws = (char*)d_ws;
    int*           rp     = (int*)(ws + off_rp);
    int*           col    = (int*)(ws + off_col);
    unsigned*      packed = (unsigned*)(ws + off_packed);
    int*           ghist  = (int*)(ws + off_ghist);
    int*           gscan  = (int*)(ws + off_gscan);
    int*           bsumR  = (int*)(ws + off_bsumR);
    ushort_t*      xb     = (ushort_t*)(ws + off_xb);
    ushort_t*      h      = (ushort_t*)(ws + off_xb);  // overlays xb (dead after GEMM1)
    unsigned char* y8     = (unsigned char*)(ws + off_y8);
    ushort_t*      zb     = (ushort_t*)(ws + off_y8);  // overlays y8 (dead after gather1)
    ushort_t*      y2b    = (ushort_t*)(ws + off_y2b);
    ushort_t*      Bt1    = (ushort_t*)(ws + off_bt1);
    ushort_t*      Bt2    = (ushort_t*)(ws + off_bt2);

    const int snb = (HTOT + SCAN_B - 1) / SCAN_B;   // 151
    const int mt64 = (N + 63) / 64;                 // 782 row slabs

    // ---- CSR build: MSD bucket sort ----
    hipLaunchKernelGGL(mhist, dim3(RNB), dim3(256), 0, stream, ei, ghist, E);
    hipLaunchKernelGGL(scan1, dim3(snb), dim3(SCAN_B), 0, stream, ghist, gscan, bsumR, HTOT);
    hipLaunchKernelGGL(scan2, dim3(1), dim3(SCAN_B), 0, stream, bsumR, snb);
    hipLaunchKernelGGL(scan3g, dim3(snb), dim3(SCAN_B), 0, stream, gscan, bsumR, HTOT);
    hipLaunchKernelGGL(mscatter, dim3(RNB), dim3(256), 0, stream, ei, gscan, packed, E);
    hipLaunchKernelGGL(bucket_sort, dim3(RNB), dim3(256), 0, stream, packed, gscan, col, rp, E);

    // ---- casts ----
    hipLaunchKernelGGL(cast_f32_bf16, dim3(2048), dim3(256), 0, stream,
                       x, xb, N * 256 / 4);
    hipLaunchKernelGGL(build_bt, dim3(768), dim3(256), 0, stream,
                       W1l, W1r, W2l, W2r, Bt1, Bt2);

    // ---- layer 1: [y8|y2b] = xb@[W1l|W1r] (+b1); h = relu(mean(y8)+y2b) --
    hipLaunchKernelGGL((gemm_astat<4, 0>), dim3(2, mt64), dim3(256), 0, stream,
                       xb, Bt1, b1, y8, y2b, (float*)nullptr, N);
    hipLaunchKernelGGL(fused_gather1, dim3((N + 3) / 4), dim3(256), 0, stream,
                       y8, y2b, rp, col, h, N);

    // ---- layer 2: [zb|out] = h@[W2l|W2r] (+b2 on out); out += mean(zb) ----
    hipLaunchKernelGGL((gemm_astat<2, 1>), dim3(2, mt64), dim3(256), 0, stream,
                       h, Bt2, b2, (unsigned char*)nullptr, zb, out, N);
    hipLaunchKernelGGL(fused_gather2, dim3((N + 3) / 4), dim3(256), 0, stream,
                       zb, rp, col, out, N);
}

// Round 11
// 182.579 us; speedup vs baseline: 1.1150x; 1.0108x over previous
//
#include <hip/hip_runtime.h>

// GraphSAGE 2-layer forward.
// Round 11: fix the 8-way LDS bank conflict found in round 10 (3.2M
// conflicts; col stride 512B = bank-wrap multiple collapsed reads into 8
// slots). B tile now stored as 4 k-chunks of [64 cols][128 B] -- row
// stride 128B + XOR (col&7)<<4, the round-4-proven 0-conflict geometry.
// A-stationary structure (A-slice in 32 VGPR loaded once, single 32KB B
// buffer, stage-before-stores + in-order vmcnt(16)) unchanged.
// CSR bucket sort, fp8 y1 gather, casts unchanged.

#define N_NODES 50000
#define N_EDGES 800000
#define RNB 196
#define REPB 4096
#define BCAP 8192

typedef unsigned short ushort_t;
typedef __attribute__((ext_vector_type(8))) short short8v;   // 8 bf16
typedef __attribute__((ext_vector_type(4))) float f32x4;
typedef __attribute__((ext_vector_type(2))) float f32x2;

__device__ __forceinline__ float b2f(ushort_t u) {
    union { unsigned int i; float f; } v; v.i = (unsigned int)u << 16; return v.f;
}
__device__ __forceinline__ ushort_t f2b(float f) {
    union { float f; unsigned int i; } v; v.f = f;
    unsigned int r = 0x7fffu + ((v.i >> 16) & 1u);   // RNE
    return (ushort_t)((v.i + r) >> 16);
}

__device__ __forceinline__ void gload_lds16(const void* gsrc, void* ldsdst) {
    auto* l3 = reinterpret_cast<__attribute__((address_space(3))) unsigned int*>(
        reinterpret_cast<uintptr_t>(ldsdst));
    __builtin_amdgcn_global_load_lds(
        reinterpret_cast<const unsigned int*>(gsrc), l3, 16, 0, 0);
}

// ---------------- CSR build via MSD bucket sort ----------------
__global__ __launch_bounds__(256) void mhist(
    const int* __restrict__ ei, int* __restrict__ ghist, int E)
{
    __shared__ int h[256];
    int t = threadIdx.x;
    h[t] = 0;
    __syncthreads();
    int base = blockIdx.x * REPB;
    int lim  = min(base + REPB, E);
    for (int i = base + t; i < lim; i += 256)
        atomicAdd(&h[ei[E + i] >> 8], 1);
    __syncthreads();
    if (t < RNB) ghist[t * RNB + blockIdx.x] = h[t];   // digit-major
}

#define SCAN_B 256
__global__ __launch_bounds__(256) void scan1(
    const int* __restrict__ in, int* __restrict__ excl,
    int* __restrict__ bsum, int N)
{
    __shared__ int s[SCAN_B];
    int t = threadIdx.x;
    int i = blockIdx.x * SCAN_B + t;
    int v = (i < N) ? in[i] : 0;
    s[t] = v;
    __syncthreads();
    for (int off = 1; off < SCAN_B; off <<= 1) {
        int add = (t >= off) ? s[t - off] : 0;
        __syncthreads();
        s[t] += add;
        __syncthreads();
    }
    if (i < N) excl[i] = s[t] - v;
    if (t == SCAN_B - 1) bsum[blockIdx.x] = s[t];
}

__global__ __launch_bounds__(256) void scan2(int* __restrict__ bsum, int nb)
{
    __shared__ int s[SCAN_B];
    int t = threadIdx.x;
    int v = (t < nb) ? bsum[t] : 0;
    s[t] = v;
    __syncthreads();
    for (int off = 1; off < 256; off <<= 1) {
        int add = (t >= off) ? s[t - off] : 0;
        __syncthreads();
        s[t] += add;
        __syncthreads();
    }
    if (t < nb) bsum[t] = s[t] - v;
}

__global__ __launch_bounds__(256) void scan3g(
    int* __restrict__ excl, const int* __restrict__ bsum, int N)
{
    int i = blockIdx.x * SCAN_B + threadIdx.x;
    if (i < N) excl[i] += bsum[blockIdx.x];
}

__global__ __launch_bounds__(256) void mscatter(
    const int* __restrict__ ei, const int* __restrict__ gscan,
    unsigned* __restrict__ packed, int E)
{
    __shared__ int cur[256];
    int t = threadIdx.x;
    if (t < RNB) cur[t] = gscan[t * RNB + blockIdx.x];
    __syncthreads();
    int base = blockIdx.x * REPB;
    int lim  = min(base + REPB, E);
    for (int i = base + t; i < lim; i += 256) {
        int d = ei[E + i], s = ei[i];
        int pos = atomicAdd(&cur[d >> 8], 1);
        packed[pos] = ((unsigned)d << 16) | (unsigned)s;
    }
}

__global__ __launch_bounds__(256) void bucket_sort(
    const unsigned* __restrict__ packed, const int* __restrict__ gscan,
    int* __restrict__ col, int* __restrict__ rp, int E)
{
    __shared__ unsigned k1[BCAP];
    __shared__ unsigned k2[BCAP];
    __shared__ int h[256], ss[256], ex[256], cur[256];

    int b = blockIdx.x, t = threadIdx.x;
    int start = gscan[b * RNB];
    int end   = (b + 1 < RNB) ? gscan[(b + 1) * RNB] : E;
    int sz    = min(end - start, BCAP);

    for (int i = t; i < sz; i += 256) k1[i] = packed[start + i];
    h[t] = 0;
    __syncthreads();
    for (int i = t; i < sz; i += 256)
        atomicAdd(&h[(k1[i] >> 16) & 255], 1);
    __syncthreads();
    ss[t] = h[t];
    __syncthreads();
    for (int off = 1; off < 256; off <<= 1) {
        int add = (t >= off) ? ss[t - off] : 0;
        __syncthreads();
        ss[t] += add;
        __syncthreads();
    }
    ex[t] = ss[t] - h[t];
    cur[t] = ex[t];
    __syncthreads();
    for (int i = t; i < sz; i += 256) {
        unsigned key = k1[i];
        int pos = atomicAdd(&cur[(key >> 16) & 255], 1);
        k2[pos] = key;
    }
    __syncthreads();
    for (int i = t; i < sz; i += 256)
        col[start + i] = (int)(k2[i] & 0xFFFFu);
    int dst = (b << 8) + t;
    if (dst <= N_NODES) rp[dst] = start + ex[t];
}

// ---------------- casts ----------------
__global__ __launch_bounds__(256) void cast_f32_bf16(
    const float* __restrict__ in, ushort_t* __restrict__ out, int n4)
{
    int i = blockIdx.x * blockDim.x + threadIdx.x;
    int stride = gridDim.x * blockDim.x;
    for (; i < n4; i += stride) {
        float4 v = ((const float4*)in)[i];
        ushort4 o;
        o.x = f2b(v.x); o.y = f2b(v.y); o.z = f2b(v.z); o.w = f2b(v.w);
        ((ushort4*)out)[i] = o;
    }
}

// Bt1[512][256] = [W1l|W1r]^T ; Bt2[256][256] = [W2l|W2r]^T  (bf16, [n][k])
__global__ __launch_bounds__(256) void build_bt(
    const float* __restrict__ W1l, const float* __restrict__ W1r,
    const float* __restrict__ W2l, const float* __restrict__ W2r,
    ushort_t* __restrict__ Bt1, ushort_t* __restrict__ Bt2)
{
    int i = blockIdx.x * 256 + threadIdx.x;
    if (i < 512 * 256) {
        int n = i >> 8, k = i & 255;
        float v = (n < 256) ? W1l[k * 256 + n] : W1r[k * 256 + (n - 256)];
        Bt1[i] = f2b(v);
    }
    int j = i - 512 * 256;
    if (j >= 0 && j < 256 * 256) {
        int n = j >> 8, k = j & 255;
        float v = (n < 128) ? W2l[k * 128 + n] : W2r[k * 128 + (n - 128)];
        Bt2[j] = f2b(v);
    }
}

// ---------------- A-stationary bf16 MFMA GEMM (conflict-free LDS) --------
// C[M, 2*NT*64] = A[M,256] @ Bt^T, Bt [n][256] bf16.
// Block: 256 thr = 4 waves x 16 rows. blockIdx.x = col group g, blockIdx.y
// = row slab. A-slice (16 rows x 256 k) resident in 8 short8v, loaded once.
// B tile stored as 4 k-chunks: chunk c = [64 cols][128 B] (k in
// [c*64,c*64+64)), row stride 128 B, XOR (col&7)<<4 -- 0-conflict geometry.
// MODE 0 (N=512): g0 -> y8 fp8 (ld 256); g1 -> y2b bf16 + bias (ld 256).
// MODE 1 (N=256): g0 -> zb bf16 (ld 128); g1 -> outf f32 + bias (ld 128).
template<int NT, int MODE>
__global__ __launch_bounds__(256, 4) void gemm_astat(
    const ushort_t* __restrict__ A, const ushort_t* __restrict__ Bt,
    const float* __restrict__ bias, unsigned char* __restrict__ out8,
    ushort_t* __restrict__ outb, float* __restrict__ outf, int M)
{
    __shared__ char Bs[4][64][128];   // 32 KB: 4 k-chunks x 64 cols x 128 B

    const int t    = threadIdx.x;
    const int lane = t & 63;
    const int wv   = t >> 6;
    const int g    = blockIdx.x;               // col group (uniform branch)
    const int row0 = blockIdx.y * 64 + wv * 16;
    const int cbase = g * NT * 64;             // first col of this group
    const int arow = min(row0 + (lane & 15), M - 1);
    const int kq   = (lane >> 4) << 3;         // k sub-slot (8 elems)

    // stage one 64-col B tile: per chunk, linear LDS dest (2 rounds of
    // 256 thr x 16 B), inverse-swizzled global source (rule #21).
    auto stage = [&](int ct) {
        #pragma unroll
        for (int c = 0; c < 4; ++c) {
            #pragma unroll
            for (int i = 0; i < 2; ++i) {
                int o     = (i * 256 + t) * 16;          // 0..8191 in chunk
                int colI  = o >> 7;
                int inner = o & 127;
                int kb    = inner ^ ((colI & 7) << 4);   // src k-byte offset
                gload_lds16(Bt + (size_t)(cbase + ct * 64 + colI) * 256
                                + c * 64 + (kb >> 1),
                            &Bs[c][0][0] + i * 4096 + wv * 1024);
            }
        }
    };

    // A-slice resident: 8 x short8v = 32 VGPR (full K)
    short8v af[8];
    #pragma unroll
    for (int ks = 0; ks < 8; ++ks)
        af[ks] = *(const short8v*)(A + (size_t)arow * 256 + ks * 32 + kq);

    stage(0);
    __builtin_amdgcn_sched_barrier(0);
    asm volatile("s_waitcnt vmcnt(0)");        // A + B(0) landed
    __builtin_amdgcn_sched_barrier(0);
    __builtin_amdgcn_s_barrier();
    __builtin_amdgcn_sched_barrier(0);

    #pragma unroll
    for (int ct = 0; ct < NT; ++ct) {
        f32x4 acc[4] = {};
        __builtin_amdgcn_s_setprio(1);
        #pragma unroll
        for (int ks = 0; ks < 8; ++ks) {
            short8v bg[4];
            #pragma unroll
            for (int nj = 0; nj < 4; ++nj) {
                int colI = (nj << 4) + (lane & 15);
                int b = (((ks & 1) << 6) + ((lane >> 4) << 4))
                        ^ ((colI & 7) << 4);
                bg[nj] = *(const short8v*)(&Bs[ks >> 1][colI][0] + b);
            }
            #pragma unroll
            for (int nj = 0; nj < 4; ++nj)
                acc[nj] = __builtin_amdgcn_mfma_f32_16x16x32_bf16(
                    af[ks], bg[nj], acc[nj], 0, 0, 0);
        }
        __builtin_amdgcn_s_setprio(0);

        if (ct + 1 < NT) {
            __builtin_amdgcn_sched_barrier(0);
            __builtin_amdgcn_s_barrier();      // all waves done reading Bs
            __builtin_amdgcn_sched_barrier(0);
            stage(ct + 1);                     // 8 loads issued FIRST
            __builtin_amdgcn_sched_barrier(0);
        }

        // stores issued AFTER stage; vmcnt retires in order
        #pragma unroll
        for (int nj = 0; nj < 4; ++nj) {
            #pragma unroll
            for (int r = 0; r < 4; ++r) {
                int row = row0 + ((lane >> 4) << 2) + r;
                if (row >= M) continue;
                int local = ct * 64 + (nj << 4) + (lane & 15);
                float v = acc[nj][r];
                if (MODE == 0) {
                    if (g == 0) {
                        unsigned p = __builtin_amdgcn_cvt_pk_fp8_f32(v, v, 0, false);
                        out8[(size_t)row * 256 + local] = (unsigned char)(p & 0xFFu);
                    } else {
                        outb[(size_t)row * 256 + local] = f2b(v + bias[local]);
                    }
                } else {
                    if (g == 0) {
                        outb[(size_t)row * 128 + local] = f2b(v);
                    } else {
                        outf[(size_t)row * 128 + local] = v + bias[local];
                    }
                }
            }
        }

        if (ct + 1 < NT) {
            __builtin_amdgcn_sched_barrier(0);
            asm volatile("s_waitcnt vmcnt(16)");   // 8 stage loads retired
            __builtin_amdgcn_sched_barrier(0);
            __builtin_amdgcn_s_barrier();          // Bs(ct+1) valid for all
            __builtin_amdgcn_sched_barrier(0);
        }
    }
}

// ---------------- fused gather 1: h = relu(mean_fp8(y1[nbr]) + y2) --------
__global__ __launch_bounds__(256) void fused_gather1(
    const unsigned char* __restrict__ y8, const ushort_t* __restrict__ y2b,
    const int* __restrict__ rp, const int* __restrict__ col,
    ushort_t* __restrict__ h, int N)
{
    int gid  = blockIdx.x * blockDim.x + threadIdx.x;
    int node = gid >> 6;
    int lane = gid & 63;
    if (node >= N) return;
    int rs = rp[node], re = rp[node + 1];

    float acc[4] = {0.f, 0.f, 0.f, 0.f};
    for (int base = rs; base < re; base += 64) {
        int m = re - base; if (m > 64) m = 64;
        int c = (lane < m) ? col[base + lane] : 0;
        int j = 0;
        for (; j + 8 <= m; j += 8) {
            unsigned tv[8];
            #pragma unroll
            for (int q = 0; q < 8; ++q) {
                int sq = __shfl(c, j + q);
                tv[q] = *(const unsigned*)(y8 + (size_t)sq * 256 + lane * 4);
            }
            #pragma unroll
            for (int q = 0; q < 8; ++q) {
                f32x2 lo = __builtin_amdgcn_cvt_pk_f32_fp8(tv[q], false);
                f32x2 hi = __builtin_amdgcn_cvt_pk_f32_fp8(tv[q], true);
                acc[0] += lo[0]; acc[1] += lo[1];
                acc[2] += hi[0]; acc[3] += hi[1];
            }
        }
        for (; j < m; ++j) {
            int sq = __shfl(c, j);
            unsigned tq = *(const unsigned*)(y8 + (size_t)sq * 256 + lane * 4);
            f32x2 lo = __builtin_amdgcn_cvt_pk_f32_fp8(tq, false);
            f32x2 hi = __builtin_amdgcn_cvt_pk_f32_fp8(tq, true);
            acc[0] += lo[0]; acc[1] += lo[1];
            acc[2] += hi[0]; acc[3] += hi[1];
        }
    }

    float s = 1.0f / (float)max(re - rs, 1);
    ushort4 t2 = *(const ushort4*)(y2b + (size_t)node * 256 + lane * 4);
    ushort4 o;
    o.x = f2b(fmaxf(acc[0] * s + b2f(t2.x), 0.f));
    o.y = f2b(fmaxf(acc[1] * s + b2f(t2.y), 0.f));
    o.z = f2b(fmaxf(acc[2] * s + b2f(t2.z), 0.f));
    o.w = f2b(fmaxf(acc[3] * s + b2f(t2.w), 0.f));
    *(ushort4*)(h + (size_t)node * 256 + lane * 4) = o;
}

// ---------------- fused gather 2: out += mean(zb[nbr]) --------------------
__global__ __launch_bounds__(256) void fused_gather2(
    const ushort_t* __restrict__ zb, const int* __restrict__ rp,
    const int* __restrict__ col, float* __restrict__ out, int N)
{
    int gid  = blockIdx.x * blockDim.x + threadIdx.x;
    int node = gid >> 6;
    int lane = gid & 63;
    if (node >= N) return;
    int rs = rp[node], re = rp[node + 1];

    float acc[2] = {0.f, 0.f};
    for (int base = rs; base < re; base += 64) {
        int m = re - base; if (m > 64) m = 64;
        int c = (lane < m) ? col[base + lane] : 0;
        int j = 0;
        for (; j + 8 <= m; j += 8) {
            ushort2 tv[8];
            #pragma unroll
            for (int q = 0; q < 8; ++q) {
                int sq = __shfl(c, j + q);
                tv[q] = *(const ushort2*)(zb + (size_t)sq * 128 + lane * 2);
            }
            #pragma unroll
            for (int q = 0; q < 8; ++q) {
                acc[0] += b2f(tv[q].x); acc[1] += b2f(tv[q].y);
            }
        }
        for (; j < m; ++j) {
            int src = __shfl(c, j);
            ushort2 tq = *(const ushort2*)(zb + (size_t)src * 128 + lane * 2);
            acc[0] += b2f(tq.x); acc[1] += b2f(tq.y);
        }
    }

    float s = 1.0f / (float)max(re - rs, 1);
    float2 p = *(float2*)(out + (size_t)node * 128 + lane * 2);
    p.x += acc[0] * s; p.y += acc[1] * s;
    *(float2*)(out + (size_t)node * 128 + lane * 2) = p;
}

extern "C" void kernel_launch(void* const* d_in, const int* in_sizes, int n_in,
                              void* d_out, int out_size, void* d_ws, size_t ws_size,
                              hipStream_t stream)
{
    const float* x   = (const float*)d_in[0];
    const int*   ei  = (const int*)d_in[1];
    const float* W1l = (const float*)d_in[2];
    const float* b1  = (const float*)d_in[3];
    const float* W1r = (const float*)d_in[4];
    const float* W2l = (const float*)d_in[5];
    const float* b2  = (const float*)d_in[6];
    const float* W2r = (const float*)d_in[7];
    float* out = (float*)d_out;

    const int N = N_NODES, E = N_EDGES;
    const int HTOT = RNB * RNB;

    // workspace layout (256 B aligned)
    const size_t off_rp     = 0;
    const size_t off_col    = 204800;
    const size_t off_packed = off_col + 3200000;
    const size_t off_ghist  = off_packed + 3200000;
    const size_t off_gscan  = off_ghist + 160000;
    const size_t off_bsumR  = off_gscan + 160000;
    const size_t off_xb     = off_bsumR + 2048;                // bf16 [N][256]; h overlays
    const size_t off_y8     = off_xb  + (size_t)N * 256 * 2;   // fp8  [N][256]; zb overlays
    const size_t off_y2b    = off_y8  + (size_t)N * 256;       // bf16 [N][256]
    const size_t off_bt1    = off_y2b + (size_t)N * 256 * 2;
    const size_t off_bt2    = off_bt1 + 512 * 256 * 2;
    const size_t required   = off_bt2 + 256 * 256 * 2;         // ~71.3 MB
    if (ws_size < required) return;

    char* ws = (char*)d_ws;
    int*           rp     = (int*)(ws + off_rp);
    int*           col    = (int*)(ws + off_col);
    unsigned*      packed = (unsigned*)(ws + off_packed);
    int*           ghist  = (int*)(ws + off_ghist);
    int*           gscan  = (int*)(ws + off_gscan);
    int*           bsumR  = (int*)(ws + off_bsumR);
    ushort_t*      xb     = (ushort_t*)(ws + off_xb);
    ushort_t*      h      = (ushort_t*)(ws + off_xb);  // overlays xb (dead after GEMM1)
    unsigned char* y8     = (unsigned char*)(ws + off_y8);
    ushort_t*      zb     = (ushort_t*)(ws + off_y8);  // overlays y8 (dead after gather1)
    ushort_t*      y2b    = (ushort_t*)(ws + off_y2b);
    ushort_t*      Bt1    = (ushort_t*)(ws + off_bt1);
    ushort_t*      Bt2    = (ushort_t*)(ws + off_bt2);

    const int snb = (HTOT + SCAN_B - 1) / SCAN_B;   // 151
    const int mt64 = (N + 63) / 64;                 // 782 row slabs

    // ---- CSR build: MSD bucket sort ----
    hipLaunchKernelGGL(mhist, dim3(RNB), dim3(256), 0, stream, ei, ghist, E);
    hipLaunchKernelGGL(scan1, dim3(snb), dim3(SCAN_B), 0, stream, ghist, gscan, bsumR, HTOT);
    hipLaunchKernelGGL(scan2, dim3(1), dim3(SCAN_B), 0, stream, bsumR, snb);
    hipLaunchKernelGGL(scan3g, dim3(snb), dim3(SCAN_B), 0, stream, gscan, bsumR, HTOT);
    hipLaunchKernelGGL(mscatter, dim3(RNB), dim3(256), 0, stream, ei, gscan, packed, E);
    hipLaunchKernelGGL(bucket_sort, dim3(RNB), dim3(256), 0, stream, packed, gscan, col, rp, E);

    // ---- casts ----
    hipLaunchKernelGGL(cast_f32_bf16, dim3(2048), dim3(256), 0, stream,
                       x, xb, N * 256 / 4);
    hipLaunchKernelGGL(build_bt, dim3(768), dim3(256), 0, stream,
                       W1l, W1r, W2l, W2r, Bt1, Bt2);

    // ---- layer 1: [y8|y2b] = xb@[W1l|W1r] (+b1); h = relu(mean(y8)+y2b) --
    hipLaunchKernelGGL((gemm_astat<4, 0>), dim3(2, mt64), dim3(256), 0, stream,
                       xb, Bt1, b1, y8, y2b, (float*)nullptr, N);
    hipLaunchKernelGGL(fused_gather1, dim3((N + 3) / 4), dim3(256), 0, stream,
                       y8, y2b, rp, col, h, N);

    // ---- layer 2: [zb|out] = h@[W2l|W2r] (+b2 on out); out += mean(zb) ----
    hipLaunchKernelGGL((gemm_astat<2, 1>), dim3(2, mt64), dim3(256), 0, stream,
                       h, Bt2, b2, (unsigned char*)nullptr, zb, out, N);
    hipLaunchKernelGGL(fused_gather2, dim3((N + 3) / 4), dim3(256), 0, stream,
                       zb, rp, col, out, N);
}